// Round 8
// baseline (158.425 us; speedup 1.0000x reference)
//
#include <hip/hip_runtime.h>

// FastFood random features, D=64, fp32 — 32-row LDS tiles for 2x occupancy.
//
// R7 post-mortem: permlane32_swap select was STILL inverted. Failure signature
// (absmax 25.5 = max|2y|: every lane kept its own value) proves the HW swap is
// vdst[32:64] <-> vsrc[0:32], so with equal inputs the PARTNER value is in
// r.x for high lanes and r.y for low lanes. R7 selected the complement.
//
// Structure (R5-proven phases, 32-row tiles): 32 rows x 64 cols = 8 KB LDS
// per wave -> 10 blocks/CU x 16 KB = 160 KB, 20 waves/CU target
// (launch_bounds(128,5)). Lane l owns HALF of row rr=l&31 (cols cb..cb+31,
// cb=32*(l>>5)). FWHT64 = 5 in-lane stages (col bits 0..4) + bit-5 stage via
// permlane32_swap (VALU pipe, no DS traffic). Stage order bit0..bit5 ==
// reference fwht order -> bitwise-exact fp32.
//
// Q layout (load/permute/store): chunk c=0..7, lane l <-> row r=4c+(l>>4),
// cols e0..e0+3 (e0=(l&15)*4). LDS swizzle col ^ ((row&15)<<2), 16B-preserving,
// conflict-free for b128; R2 b32 gathers are 16-lane broadcasts.
// Same-wave DS program order provides all RAW ordering (tile is wave-private;
// no fences, no barriers). Next tile's globals prefetched after R2.

typedef float f32x4 __attribute__((ext_vector_type(4)));
typedef unsigned u32x2 __attribute__((ext_vector_type(2)));

// Value of v in partner lane l^32 (all 64 lanes active).
// HW: v_permlane32_swap_b32 vdst, vsrc swaps vdst[32:64] <-> vsrc[0:32]:
//   new_vdst: lanes<32 own,      lanes>=32 partner  (r.x)
//   new_vsrc: lanes<32 partner,  lanes>=32 own      (r.y)
__device__ __forceinline__ float partner32(float v, bool hh) {
    const unsigned u = __float_as_uint(v);
    const u32x2 r = __builtin_amdgcn_permlane32_swap(u, u, false, false);
    return __uint_as_float(hh ? r.x : r.y);
}

#define FSTAGE32(H)                                                 \
    _Pragma("unroll")                                               \
    for (int i = 0; i < 32; i += 2*(H)) {                           \
        _Pragma("unroll")                                           \
        for (int j = 0; j < (H); ++j) {                             \
            const float a = y[i+j], b = y[i+j+(H)];                 \
            y[i+j] = a + b; y[i+j+(H)] = a - b;                     \
        }                                                           \
    }

__global__ __launch_bounds__(128, 5) void fastfood_kernel(
    const float* __restrict__ x,
    const float* __restrict__ Bv,
    const float* __restrict__ Gv,
    const float* __restrict__ Sv,
    const int*   __restrict__ Pv,
    float* __restrict__ out,
    int ntiles)
{
    __shared__ float lds_all[2 * 2048];   // 16 KB/block: 8 KB per wave
    const int l  = threadIdx.x & 63;
    const int wv = threadIdx.x >> 6;
    float* lds = &lds_all[wv * 2048];

    const int wid    = blockIdx.x * 2 + wv;
    const int nwaves = gridDim.x * 2;

    const int hi = l >> 4;        // 0..3
    const int lo = l & 15;        // 0..15
    const int e0 = lo << 2;       // Q-layout col group
    const int rr = l & 31;        // R-layout row
    const bool hh = (l >= 32);    // R-layout column half
    const int cb = hh ? 32 : 0;   // column base
    const int swzr = (rr & 15) << 2;

    const float c1 = 0.35355339059327373f;  // 64^(-1/4)
    const float c2 = 0.125f;                // sqrt(1/64)

    const float bs0 = Bv[e0+0]*c1, bs1 = Bv[e0+1]*c1, bs2 = Bv[e0+2]*c1, bs3 = Bv[e0+3]*c1;
    const float gg0 = Gv[e0+0],    gg1 = Gv[e0+1],    gg2 = Gv[e0+2],    gg3 = Gv[e0+3];
    const float ss0 = Sv[e0+0]*c2, ss1 = Sv[e0+1]*c2, ss2 = Sv[e0+2]*c2, ss3 = Sv[e0+3]*c2;
    const int   p0  = Pv[e0+0],    p1  = Pv[e0+1],    p2  = Pv[e0+2],    p3  = Pv[e0+3];

    const f32x4* __restrict__ xin  = (const f32x4*)x;
    f32x4* __restrict__       yout = (f32x4*)out;

    int t = wid;
    if (t >= ntiles) return;

    // Prologue: load first tile (32 rows = 512 f32x4, 8 chunks).
    f32x4 st[8];
    {
        const long long tb = (long long)t * 512;
        #pragma unroll
        for (int c = 0; c < 8; ++c) st[c] = xin[tb + c*64 + l];
    }

    for (; t < ntiles; t += nwaves) {
        const long long tb = (long long)t * 512;

        // ---- W1: *B*c1, write Q layout ----
        #pragma unroll
        for (int c = 0; c < 8; ++c) {
            const int r = 4*c + hi;
            f32x4 v = st[c];
            v.x *= bs0; v.y *= bs1; v.z *= bs2; v.w *= bs3;
            *(f32x4*)&lds[r*64 + (e0 ^ ((r & 15) << 2))] = v;
        }

        // ---- R1: lane reads its half-row (cols cb..cb+31 of row rr) ----
        float y[32];
        #pragma unroll
        for (int k = 0; k < 8; ++k) {
            const f32x4 v = *(const f32x4*)&lds[rr*64 + ((cb + 4*k) ^ swzr)];
            y[4*k+0] = v.x; y[4*k+1] = v.y; y[4*k+2] = v.z; y[4*k+3] = v.w;
        }

        // ---- FWHT #1: bits 0..4 in-lane, bit 5 via permlane32_swap ----
        FSTAGE32(1) FSTAGE32(2) FSTAGE32(4) FSTAGE32(8) FSTAGE32(16)
        #pragma unroll
        for (int i = 0; i < 32; ++i) {
            const float opp = partner32(y[i], hh);
            y[i] = hh ? (opp - y[i]) : (y[i] + opp);
        }

        // ---- W2: write y1 back (half-row) ----
        #pragma unroll
        for (int k = 0; k < 8; ++k) {
            f32x4 v;
            v.x = y[4*k+0]; v.y = y[4*k+1]; v.z = y[4*k+2]; v.w = y[4*k+3];
            *(f32x4*)&lds[rr*64 + ((cb + 4*k) ^ swzr)] = v;
        }

        // ---- R2: permuted gather + *G, write Q layout ----
        // (reads of rows 4c..4c+3 precede the write to them: same-wave DS order)
        #pragma unroll
        for (int c = 0; c < 8; ++c) {
            const int r  = 4*c + hi;
            const int rb = r * 64;
            const int sw = (r & 15) << 2;
            const float a0 = lds[rb + (p0 ^ sw)];
            const float a1 = lds[rb + (p1 ^ sw)];
            const float a2 = lds[rb + (p2 ^ sw)];
            const float a3 = lds[rb + (p3 ^ sw)];
            f32x4 v;
            v.x = a0 * gg0; v.y = a1 * gg1; v.z = a2 * gg2; v.w = a3 * gg3;
            *(f32x4*)&lds[rb + (e0 ^ sw)] = v;
        }

        // ---- prefetch next tile (wave-uniform guard) ----
        if (t + nwaves < ntiles) {
            const long long nb = (long long)(t + nwaves) * 512;
            #pragma unroll
            for (int c = 0; c < 8; ++c) st[c] = xin[nb + c*64 + l];
        }

        // ---- R3: read y2 half-row ----
        #pragma unroll
        for (int k = 0; k < 8; ++k) {
            const f32x4 v = *(const f32x4*)&lds[rr*64 + ((cb + 4*k) ^ swzr)];
            y[4*k+0] = v.x; y[4*k+1] = v.y; y[4*k+2] = v.z; y[4*k+3] = v.w;
        }

        // ---- FWHT #2 ----
        FSTAGE32(1) FSTAGE32(2) FSTAGE32(4) FSTAGE32(8) FSTAGE32(16)
        #pragma unroll
        for (int i = 0; i < 32; ++i) {
            const float opp = partner32(y[i], hh);
            y[i] = hh ? (opp - y[i]) : (y[i] + opp);
        }

        // ---- W4: write back (half-row) ----
        #pragma unroll
        for (int k = 0; k < 8; ++k) {
            f32x4 v;
            v.x = y[4*k+0]; v.y = y[4*k+1]; v.z = y[4*k+2]; v.w = y[4*k+3];
            *(f32x4*)&lds[rr*64 + ((cb + 4*k) ^ swzr)] = v;
        }

        // ---- R4: Q read, *S*c2, nontemporal store ----
        #pragma unroll
        for (int c = 0; c < 8; ++c) {
            const int r = 4*c + hi;
            f32x4 v = *(const f32x4*)&lds[r*64 + (e0 ^ ((r & 15) << 2))];
            v.x *= ss0; v.y *= ss1; v.z *= ss2; v.w *= ss3;
            __builtin_nontemporal_store(v, &yout[tb + c*64 + l]);
        }
    }
}

extern "C" void kernel_launch(void* const* d_in, const int* in_sizes, int n_in,
                              void* d_out, int out_size, void* d_ws, size_t ws_size,
                              hipStream_t stream) {
    const float* x = (const float*)d_in[0];
    const float* B = (const float*)d_in[1];
    const float* G = (const float*)d_in[2];
    const float* S = (const float*)d_in[3];
    const int*   P = (const int*)d_in[4];
    float* out = (float*)d_out;

    const int ntiles = in_sizes[0] / 2048;   // 32 rows x 64 floats per tile

    const int block = 128;   // 2 waves, 16 KB LDS -> 10 blocks/CU, 20 waves/CU
    const int grid  = 2560;  // 10 per CU x 256 CUs; grid-stride over 16384 tiles
    fastfood_kernel<<<grid, block, 0, stream>>>(x, B, G, S, P, out, ntiles);
}

// Round 9
// 111.240 us; speedup vs baseline: 1.4242x; 1.4242x over previous
//
#include <hip/hip_runtime.h>

// FastFood random features, D=64, fp32 — 32-row LDS tiles.
//
// R8 post-mortem: launch_bounds(128,5) clamped VGPR to 48 -> y[32]+st[8]
// spilled to scratch: FETCH 65->257MB, WRITE 131->364MB, 3x slower. The
// kernel itself is correct (absmax 0.0; permlane32_swap partner confirmed
// = hh ? r.x : r.y). Fix: launch_bounds(128,4) -> 128-VGPR budget, ~100 live
// regs fit with zero spill; occupancy 16 waves/CU (VGPR-capped; LDS allows 20,
// R5 had only 10).
//
// Structure: 32 rows x 64 cols = 8 KB LDS per wave. Lane l owns HALF of row
// rr=l&31 (cols cb..cb+31, cb=32*(l>>5)). FWHT64 = 5 in-lane stages (col bits
// 0..4) + bit-5 stage via permlane32_swap (VALU pipe, no DS traffic). Stage
// order bit0..bit5 == reference fwht order -> bitwise-exact fp32.
//
// Q layout (load/permute/store): chunk c=0..7, lane l <-> row r=4c+(l>>4),
// cols e0..e0+3 (e0=(l&15)*4). LDS swizzle col ^ ((row&15)<<2), 16B-preserving,
// conflict-free for b128; R2 b32 gathers are 16-lane broadcasts.
// Same-wave DS program order provides all RAW ordering (tile is wave-private;
// no fences, no barriers). Next tile's globals prefetched after R2.

typedef float f32x4 __attribute__((ext_vector_type(4)));
typedef unsigned u32x2 __attribute__((ext_vector_type(2)));

// Value of v in partner lane l^32 (all 64 lanes active).
// HW: v_permlane32_swap_b32 vdst, vsrc swaps vdst[32:64] <-> vsrc[0:32]:
//   new_vdst (r.x): lanes<32 own,      lanes>=32 partner
//   new_vsrc (r.y): lanes<32 partner,  lanes>=32 own
__device__ __forceinline__ float partner32(float v, bool hh) {
    const unsigned u = __float_as_uint(v);
    const u32x2 r = __builtin_amdgcn_permlane32_swap(u, u, false, false);
    return __uint_as_float(hh ? r.x : r.y);
}

#define FSTAGE32(H)                                                 \
    _Pragma("unroll")                                               \
    for (int i = 0; i < 32; i += 2*(H)) {                           \
        _Pragma("unroll")                                           \
        for (int j = 0; j < (H); ++j) {                             \
            const float a = y[i+j], b = y[i+j+(H)];                 \
            y[i+j] = a + b; y[i+j+(H)] = a - b;                     \
        }                                                           \
    }

__global__ __launch_bounds__(128, 4) void fastfood_kernel(
    const float* __restrict__ x,
    const float* __restrict__ Bv,
    const float* __restrict__ Gv,
    const float* __restrict__ Sv,
    const int*   __restrict__ Pv,
    float* __restrict__ out,
    int ntiles)
{
    __shared__ float lds_all[2 * 2048];   // 16 KB/block: 8 KB per wave
    const int l  = threadIdx.x & 63;
    const int wv = threadIdx.x >> 6;
    float* lds = &lds_all[wv * 2048];

    const int wid    = blockIdx.x * 2 + wv;
    const int nwaves = gridDim.x * 2;

    const int hi = l >> 4;        // 0..3
    const int lo = l & 15;        // 0..15
    const int e0 = lo << 2;       // Q-layout col group
    const int rr = l & 31;        // R-layout row
    const bool hh = (l >= 32);    // R-layout column half
    const int cb = hh ? 32 : 0;   // column base
    const int swzr = (rr & 15) << 2;

    const float c1 = 0.35355339059327373f;  // 64^(-1/4)
    const float c2 = 0.125f;                // sqrt(1/64)

    const float bs0 = Bv[e0+0]*c1, bs1 = Bv[e0+1]*c1, bs2 = Bv[e0+2]*c1, bs3 = Bv[e0+3]*c1;
    const float gg0 = Gv[e0+0],    gg1 = Gv[e0+1],    gg2 = Gv[e0+2],    gg3 = Gv[e0+3];
    const float ss0 = Sv[e0+0]*c2, ss1 = Sv[e0+1]*c2, ss2 = Sv[e0+2]*c2, ss3 = Sv[e0+3]*c2;
    const int   p0  = Pv[e0+0],    p1  = Pv[e0+1],    p2  = Pv[e0+2],    p3  = Pv[e0+3];

    const f32x4* __restrict__ xin  = (const f32x4*)x;
    f32x4* __restrict__       yout = (f32x4*)out;

    int t = wid;
    if (t >= ntiles) return;

    // Prologue: load first tile (32 rows = 512 f32x4, 8 chunks).
    f32x4 st[8];
    {
        const long long tb = (long long)t * 512;
        #pragma unroll
        for (int c = 0; c < 8; ++c) st[c] = xin[tb + c*64 + l];
    }

    for (; t < ntiles; t += nwaves) {
        const long long tb = (long long)t * 512;

        // ---- W1: *B*c1, write Q layout ----
        #pragma unroll
        for (int c = 0; c < 8; ++c) {
            const int r = 4*c + hi;
            f32x4 v = st[c];
            v.x *= bs0; v.y *= bs1; v.z *= bs2; v.w *= bs3;
            *(f32x4*)&lds[r*64 + (e0 ^ ((r & 15) << 2))] = v;
        }

        // ---- R1: lane reads its half-row (cols cb..cb+31 of row rr) ----
        float y[32];
        #pragma unroll
        for (int k = 0; k < 8; ++k) {
            const f32x4 v = *(const f32x4*)&lds[rr*64 + ((cb + 4*k) ^ swzr)];
            y[4*k+0] = v.x; y[4*k+1] = v.y; y[4*k+2] = v.z; y[4*k+3] = v.w;
        }

        // ---- FWHT #1: bits 0..4 in-lane, bit 5 via permlane32_swap ----
        FSTAGE32(1) FSTAGE32(2) FSTAGE32(4) FSTAGE32(8) FSTAGE32(16)
        #pragma unroll
        for (int i = 0; i < 32; ++i) {
            const float opp = partner32(y[i], hh);
            y[i] = hh ? (opp - y[i]) : (y[i] + opp);
        }

        // ---- W2: write y1 back (half-row) ----
        #pragma unroll
        for (int k = 0; k < 8; ++k) {
            f32x4 v;
            v.x = y[4*k+0]; v.y = y[4*k+1]; v.z = y[4*k+2]; v.w = y[4*k+3];
            *(f32x4*)&lds[rr*64 + ((cb + 4*k) ^ swzr)] = v;
        }

        // ---- R2: permuted gather + *G, write Q layout ----
        // (reads of rows 4c..4c+3 precede the write to them: same-wave DS order)
        #pragma unroll
        for (int c = 0; c < 8; ++c) {
            const int r  = 4*c + hi;
            const int rb = r * 64;
            const int sw = (r & 15) << 2;
            const float a0 = lds[rb + (p0 ^ sw)];
            const float a1 = lds[rb + (p1 ^ sw)];
            const float a2 = lds[rb + (p2 ^ sw)];
            const float a3 = lds[rb + (p3 ^ sw)];
            f32x4 v;
            v.x = a0 * gg0; v.y = a1 * gg1; v.z = a2 * gg2; v.w = a3 * gg3;
            *(f32x4*)&lds[rb + (e0 ^ sw)] = v;
        }

        // ---- prefetch next tile (wave-uniform guard) ----
        if (t + nwaves < ntiles) {
            const long long nb = (long long)(t + nwaves) * 512;
            #pragma unroll
            for (int c = 0; c < 8; ++c) st[c] = xin[nb + c*64 + l];
        }

        // ---- R3: read y2 half-row ----
        #pragma unroll
        for (int k = 0; k < 8; ++k) {
            const f32x4 v = *(const f32x4*)&lds[rr*64 + ((cb + 4*k) ^ swzr)];
            y[4*k+0] = v.x; y[4*k+1] = v.y; y[4*k+2] = v.z; y[4*k+3] = v.w;
        }

        // ---- FWHT #2 ----
        FSTAGE32(1) FSTAGE32(2) FSTAGE32(4) FSTAGE32(8) FSTAGE32(16)
        #pragma unroll
        for (int i = 0; i < 32; ++i) {
            const float opp = partner32(y[i], hh);
            y[i] = hh ? (opp - y[i]) : (y[i] + opp);
        }

        // ---- W4: write back (half-row) ----
        #pragma unroll
        for (int k = 0; k < 8; ++k) {
            f32x4 v;
            v.x = y[4*k+0]; v.y = y[4*k+1]; v.z = y[4*k+2]; v.w = y[4*k+3];
            *(f32x4*)&lds[rr*64 + ((cb + 4*k) ^ swzr)] = v;
        }

        // ---- R4: Q read, *S*c2, nontemporal store ----
        #pragma unroll
        for (int c = 0; c < 8; ++c) {
            const int r = 4*c + hi;
            f32x4 v = *(const f32x4*)&lds[r*64 + (e0 ^ ((r & 15) << 2))];
            v.x *= ss0; v.y *= ss1; v.z *= ss2; v.w *= ss3;
            __builtin_nontemporal_store(v, &yout[tb + c*64 + l]);
        }
    }
}

extern "C" void kernel_launch(void* const* d_in, const int* in_sizes, int n_in,
                              void* d_out, int out_size, void* d_ws, size_t ws_size,
                              hipStream_t stream) {
    const float* x = (const float*)d_in[0];
    const float* B = (const float*)d_in[1];
    const float* G = (const float*)d_in[2];
    const float* S = (const float*)d_in[3];
    const int*   P = (const int*)d_in[4];
    float* out = (float*)d_out;

    const int ntiles = in_sizes[0] / 2048;   // 32 rows x 64 floats per tile

    const int block = 128;   // 2 waves, 16 KB LDS; VGPR-capped 8 blocks/CU
    const int grid  = 2048;  // 8 per CU x 256 CUs; grid-stride over 16384 tiles
    fastfood_kernel<<<grid, block, 0, stream>>>(x, B, G, S, P, out, ntiles);
}

// Round 10
// 47.171 us; speedup vs baseline: 3.3585x; 2.3582x over previous
//
#include <hip/hip_runtime.h>

// FastFood random features, D=64, fp32 — 32-row LDS tiles.
//
// R9 post-mortem: __launch_bounds__(128,N) on this toolchain clamps VGPR to
// ~256/N (N=5 -> 48, N=4 -> 64), NOT 512/N — both rounds spilled y[32]+st[8]
// to scratch (FETCH 220MB / WRITE 294MB of extra traffic). Fix: drop the
// second arg; natural allocation (~100-128 VGPR, cf. R5's 144 with a 2x
// bigger tile) fits live state with zero spill, and <=128 VGPR gives
// 4 waves/SIMD = 16 waves/CU anyway (LDS allows 20).
//
// Structure: 32 rows x 64 cols = 8 KB LDS per wave. Lane l owns HALF of row
// rr=l&31 (cols cb..cb+31, cb=32*(l>>5)). FWHT64 = 5 in-lane stages (col bits
// 0..4) + bit-5 stage via permlane32_swap (VALU pipe, no DS traffic; partner
// value = hh ? r.x : r.y, HW-verified R8). Stage order bit0..bit5 ==
// reference fwht order -> bitwise-exact fp32 (absmax 0.0 in R8/R9).
//
// Q layout (load/permute/store): chunk c=0..7, lane l <-> row r=4c+(l>>4),
// cols e0..e0+3 (e0=(l&15)*4). LDS swizzle col ^ ((row&15)<<2), 16B-preserving,
// conflict-free for b128; R2 b32 gathers are 16-lane broadcasts.
// Same-wave DS program order provides all RAW ordering (tile is wave-private;
// no fences, no barriers). Next tile's globals prefetched after R2.

typedef float f32x4 __attribute__((ext_vector_type(4)));
typedef unsigned u32x2 __attribute__((ext_vector_type(2)));

// Value of v in partner lane l^32 (all 64 lanes active).
// HW: v_permlane32_swap_b32 vdst, vsrc swaps vdst[32:64] <-> vsrc[0:32]:
//   new_vdst (r.x): lanes<32 own,      lanes>=32 partner
//   new_vsrc (r.y): lanes<32 partner,  lanes>=32 own
__device__ __forceinline__ float partner32(float v, bool hh) {
    const unsigned u = __float_as_uint(v);
    const u32x2 r = __builtin_amdgcn_permlane32_swap(u, u, false, false);
    return __uint_as_float(hh ? r.x : r.y);
}

#define FSTAGE32(H)                                                 \
    _Pragma("unroll")                                               \
    for (int i = 0; i < 32; i += 2*(H)) {                           \
        _Pragma("unroll")                                           \
        for (int j = 0; j < (H); ++j) {                             \
            const float a = y[i+j], b = y[i+j+(H)];                 \
            y[i+j] = a + b; y[i+j+(H)] = a - b;                     \
        }                                                           \
    }

__global__ __launch_bounds__(128) void fastfood_kernel(
    const float* __restrict__ x,
    const float* __restrict__ Bv,
    const float* __restrict__ Gv,
    const float* __restrict__ Sv,
    const int*   __restrict__ Pv,
    float* __restrict__ out,
    int ntiles)
{
    __shared__ float lds_all[2 * 2048];   // 16 KB/block: 8 KB per wave
    const int l  = threadIdx.x & 63;
    const int wv = threadIdx.x >> 6;
    float* lds = &lds_all[wv * 2048];

    const int wid    = blockIdx.x * 2 + wv;
    const int nwaves = gridDim.x * 2;

    const int hi = l >> 4;        // 0..3
    const int lo = l & 15;        // 0..15
    const int e0 = lo << 2;       // Q-layout col group
    const int rr = l & 31;        // R-layout row
    const bool hh = (l >= 32);    // R-layout column half
    const int cb = hh ? 32 : 0;   // column base
    const int swzr = (rr & 15) << 2;

    const float c1 = 0.35355339059327373f;  // 64^(-1/4)
    const float c2 = 0.125f;                // sqrt(1/64)

    const float bs0 = Bv[e0+0]*c1, bs1 = Bv[e0+1]*c1, bs2 = Bv[e0+2]*c1, bs3 = Bv[e0+3]*c1;
    const float gg0 = Gv[e0+0],    gg1 = Gv[e0+1],    gg2 = Gv[e0+2],    gg3 = Gv[e0+3];
    const float ss0 = Sv[e0+0]*c2, ss1 = Sv[e0+1]*c2, ss2 = Sv[e0+2]*c2, ss3 = Sv[e0+3]*c2;
    const int   p0  = Pv[e0+0],    p1  = Pv[e0+1],    p2  = Pv[e0+2],    p3  = Pv[e0+3];

    const f32x4* __restrict__ xin  = (const f32x4*)x;
    f32x4* __restrict__       yout = (f32x4*)out;

    int t = wid;
    if (t >= ntiles) return;

    // Prologue: load first tile (32 rows = 512 f32x4, 8 chunks).
    f32x4 st[8];
    {
        const long long tb = (long long)t * 512;
        #pragma unroll
        for (int c = 0; c < 8; ++c) st[c] = xin[tb + c*64 + l];
    }

    for (; t < ntiles; t += nwaves) {
        const long long tb = (long long)t * 512;

        // ---- W1: *B*c1, write Q layout ----
        #pragma unroll
        for (int c = 0; c < 8; ++c) {
            const int r = 4*c + hi;
            f32x4 v = st[c];
            v.x *= bs0; v.y *= bs1; v.z *= bs2; v.w *= bs3;
            *(f32x4*)&lds[r*64 + (e0 ^ ((r & 15) << 2))] = v;
        }

        // ---- R1: lane reads its half-row (cols cb..cb+31 of row rr) ----
        float y[32];
        #pragma unroll
        for (int k = 0; k < 8; ++k) {
            const f32x4 v = *(const f32x4*)&lds[rr*64 + ((cb + 4*k) ^ swzr)];
            y[4*k+0] = v.x; y[4*k+1] = v.y; y[4*k+2] = v.z; y[4*k+3] = v.w;
        }

        // ---- FWHT #1: bits 0..4 in-lane, bit 5 via permlane32_swap ----
        FSTAGE32(1) FSTAGE32(2) FSTAGE32(4) FSTAGE32(8) FSTAGE32(16)
        #pragma unroll
        for (int i = 0; i < 32; ++i) {
            const float opp = partner32(y[i], hh);
            y[i] = hh ? (opp - y[i]) : (y[i] + opp);
        }

        // ---- W2: write y1 back (half-row) ----
        #pragma unroll
        for (int k = 0; k < 8; ++k) {
            f32x4 v;
            v.x = y[4*k+0]; v.y = y[4*k+1]; v.z = y[4*k+2]; v.w = y[4*k+3];
            *(f32x4*)&lds[rr*64 + ((cb + 4*k) ^ swzr)] = v;
        }

        // ---- R2: permuted gather + *G, write Q layout ----
        // (reads of rows 4c..4c+3 precede the write to them: same-wave DS order)
        #pragma unroll
        for (int c = 0; c < 8; ++c) {
            const int r  = 4*c + hi;
            const int rb = r * 64;
            const int sw = (r & 15) << 2;
            const float a0 = lds[rb + (p0 ^ sw)];
            const float a1 = lds[rb + (p1 ^ sw)];
            const float a2 = lds[rb + (p2 ^ sw)];
            const float a3 = lds[rb + (p3 ^ sw)];
            f32x4 v;
            v.x = a0 * gg0; v.y = a1 * gg1; v.z = a2 * gg2; v.w = a3 * gg3;
            *(f32x4*)&lds[rb + (e0 ^ sw)] = v;
        }

        // ---- prefetch next tile (wave-uniform guard) ----
        if (t + nwaves < ntiles) {
            const long long nb = (long long)(t + nwaves) * 512;
            #pragma unroll
            for (int c = 0; c < 8; ++c) st[c] = xin[nb + c*64 + l];
        }

        // ---- R3: read y2 half-row ----
        #pragma unroll
        for (int k = 0; k < 8; ++k) {
            const f32x4 v = *(const f32x4*)&lds[rr*64 + ((cb + 4*k) ^ swzr)];
            y[4*k+0] = v.x; y[4*k+1] = v.y; y[4*k+2] = v.z; y[4*k+3] = v.w;
        }

        // ---- FWHT #2 ----
        FSTAGE32(1) FSTAGE32(2) FSTAGE32(4) FSTAGE32(8) FSTAGE32(16)
        #pragma unroll
        for (int i = 0; i < 32; ++i) {
            const float opp = partner32(y[i], hh);
            y[i] = hh ? (opp - y[i]) : (y[i] + opp);
        }

        // ---- W4: write back (half-row) ----
        #pragma unroll
        for (int k = 0; k < 8; ++k) {
            f32x4 v;
            v.x = y[4*k+0]; v.y = y[4*k+1]; v.z = y[4*k+2]; v.w = y[4*k+3];
            *(f32x4*)&lds[rr*64 + ((cb + 4*k) ^ swzr)] = v;
        }

        // ---- R4: Q read, *S*c2, nontemporal store ----
        #pragma unroll
        for (int c = 0; c < 8; ++c) {
            const int r = 4*c + hi;
            f32x4 v = *(const f32x4*)&lds[r*64 + (e0 ^ ((r & 15) << 2))];
            v.x *= ss0; v.y *= ss1; v.z *= ss2; v.w *= ss3;
            __builtin_nontemporal_store(v, &yout[tb + c*64 + l]);
        }
    }
}

extern "C" void kernel_launch(void* const* d_in, const int* in_sizes, int n_in,
                              void* d_out, int out_size, void* d_ws, size_t ws_size,
                              hipStream_t stream) {
    const float* x = (const float*)d_in[0];
    const float* B = (const float*)d_in[1];
    const float* G = (const float*)d_in[2];
    const float* S = (const float*)d_in[3];
    const int*   P = (const int*)d_in[4];
    float* out = (float*)d_out;

    const int ntiles = in_sizes[0] / 2048;   // 32 rows x 64 floats per tile

    const int block = 128;   // 2 waves, 16 KB LDS
    const int grid  = 2560;  // grid-stride over 16384 tiles
    fastfood_kernel<<<grid, block, 0, stream>>>(x, B, G, S, P, out, ntiles);
}